// Round 14
// baseline (621.267 us; speedup 1.0000x reference)
//
#include <hip/hip_runtime.h>

#define HH 192
#define WW 192
#define CC 128
#define BB 8
#define HW (HH * WW)          // 36864
#define OC 8
#define NPIX (BB * HW)        // 294912 per BN channel
#define YCHUNK (OC * BB * HW) // elements per y buffer
#define X0ROW 24576           // elems per (b,row): 2par*6ut*2048
#define X1ROW 28672           // elems per (b,row): 2par*7vt*2048

typedef __attribute__((ext_vector_type(8))) short bf16x8;
typedef __attribute__((ext_vector_type(4))) float f32x4;

__device__ __forceinline__ unsigned short f2bf(float f) {
    unsigned int u = __float_as_uint(f);
    u += 0x7fffu + ((u >> 16) & 1u);          // RNE
    return (unsigned short)(u >> 16);
}
__device__ __forceinline__ float bf2f(unsigned short u) {
    return __uint_as_float(((unsigned int)u) << 16);
}

// ---------------------------------------------------------------------------
// k_pack: fp32 [b][c][h][w] -> bf16 fragment-ordered tiles (r8-proven uint4).
// ---------------------------------------------------------------------------
__global__ __launch_bounds__(256) void k_pack(
    const float* __restrict__ x0, const float* __restrict__ x1,
    unsigned short* __restrict__ x0t, unsigned short* __restrict__ x1t)
{
    const int h = blockIdx.x, b = blockIdx.y, t = blockIdx.z;
    const float* src = t ? x1 : x0;
    __shared__ unsigned short lds[WW * 130];

    for (int idx = threadIdx.x; idx < CC * WW; idx += 256) {
        const int w = idx % WW, c = idx / WW;      // consecutive w per lane
        lds[w * 130 + c] = f2bf(src[((size_t)(b * CC + c) * HH + h) * WW + w]);
    }
    __syncthreads();

    if (t == 0) {
        uint4* dst = (uint4*)(x0t + (size_t)(b * HH + h) * X0ROW);
        for (int f8 = threadIdx.x; f8 < X0ROW / 8; f8 += 256) {
            const int pxl = f8 & 15;
            const int kg  = (f8 >> 4) & 3;
            const int q   = (f8 >> 6) & 3;
            const int pu  = f8 >> 8;               // par*6 + ut
            const int ut  = pu % 6, par = pu / 6;
            const int px  = 2 * (16 * ut + pxl) + par;
            const unsigned short* s0 = &lds[px * 130 + q * 32 + kg * 8];
            uint4 v;
            v.x = s0[0] | ((unsigned int)s0[1] << 16);
            v.y = s0[2] | ((unsigned int)s0[3] << 16);
            v.z = s0[4] | ((unsigned int)s0[5] << 16);
            v.w = s0[6] | ((unsigned int)s0[7] << 16);
            dst[f8] = v;
        }
    } else {
        uint4* dst = (uint4*)(x1t + (size_t)(b * HH + h) * X1ROW);
        for (int f8 = threadIdx.x; f8 < X1ROW / 8; f8 += 256) {
            const int pxl = f8 & 15;
            const int kg  = (f8 >> 4) & 3;
            const int q   = (f8 >> 6) & 3;
            const int pv  = f8 >> 8;               // par*7 + vt
            const int vt  = pv % 7, par = pv / 7;
            const int v   = 16 * vt - 8 + pxl;
            uint4 val = {0u, 0u, 0u, 0u};
            if (v >= 0 && v < 96) {
                const int px = 2 * v + par;
                const unsigned short* s0 = &lds[px * 130 + q * 32 + kg * 8];
                val.x = s0[0] | ((unsigned int)s0[1] << 16);
                val.y = s0[2] | ((unsigned int)s0[3] << 16);
                val.z = s0[4] | ((unsigned int)s0[5] << 16);
                val.w = s0[6] | ((unsigned int)s0[7] << 16);
            }
            dst[f8] = val;
        }
    }
}

// ---------------------------------------------------------------------------
// Pipelined band-GEMM step macros (r9, correctness-verified).
// step S in [0,16): ir = S>>1, par = S&1. 12 dense loads / 8 MFMAs.
// ---------------------------------------------------------------------------
#define LOAD_STEP(FA, FB, PI, S)                                              \
  do {                                                                        \
    const int irL = (S) >> 1, parL = (S) & 1;                                 \
    const int iL  = i0 - 1 + irL;                                             \
    const int rL  = iL + 2 * (PI) - 10;                                       \
    const int icL = min(max(iL, 0), HH - 1);                                  \
    const int rcL = min(max(rL, 0), HH - 1);                                  \
    const unsigned short* paL = x0b + (size_t)icL * X0ROW + lane * 8          \
                              + (parL * 6 + wave) * 2048;                     \
    FA[0] = *(const bf16x8*)(paL);                                            \
    FA[1] = *(const bf16x8*)(paL + 512);                                      \
    FA[2] = *(const bf16x8*)(paL + 1024);                                     \
    FA[3] = *(const bf16x8*)(paL + 1536);                                     \
    const unsigned short* pbL = x1b + (size_t)rcL * X1ROW + lane * 8          \
                              + (parL * 7 + wave) * 2048;                     \
    FB[0][0] = *(const bf16x8*)(pbL);                                         \
    FB[0][1] = *(const bf16x8*)(pbL + 512);                                   \
    FB[0][2] = *(const bf16x8*)(pbL + 1024);                                  \
    FB[0][3] = *(const bf16x8*)(pbL + 1536);                                  \
    FB[1][0] = *(const bf16x8*)(pbL + 2048);                                  \
    FB[1][1] = *(const bf16x8*)(pbL + 2560);                                  \
    FB[1][2] = *(const bf16x8*)(pbL + 3072);                                  \
    FB[1][3] = *(const bf16x8*)(pbL + 3584);                                  \
  } while (0)

#define COMPUTE_STEP(FA, FB, PI, S)                                           \
  do {                                                                        \
    const int irC = (S) >> 1, parC = (S) & 1;                                 \
    const int iC  = i0 - 1 + irC;                                             \
    const int rC  = iC + 2 * (PI) - 10;                                       \
    const bool gvC = (iC >= 0) && (iC < HH) && (rC >= 0) && (rC < HH);        \
    _Pragma("unroll")                                                         \
    for (int vtl = 0; vtl < 2; ++vtl) {                                       \
      f32x4 c = {0.f, 0.f, 0.f, 0.f};                                         \
      c = __builtin_amdgcn_mfma_f32_16x16x32_bf16(FA[0], FB[vtl][0], c,0,0,0);\
      c = __builtin_amdgcn_mfma_f32_16x16x32_bf16(FA[1], FB[vtl][1], c,0,0,0);\
      c = __builtin_amdgcn_mfma_f32_16x16x32_bf16(FA[2], FB[vtl][2], c,0,0,0);\
      c = __builtin_amdgcn_mfma_f32_16x16x32_bf16(FA[3], FB[vtl][3], c,0,0,0);\
      const int vC = u0 - 8 + 16 * vtl + ln15;                                \
      _Pragma("unroll")                                                       \
      for (int rg = 0; rg < 4; ++rg) {                                        \
        const int uC  = u0 + kg * 4 + rg;                                     \
        const int pjC = vC - uC + 5;                                          \
        if (pjC >= 0 && pjC < 11)                                             \
          corr[irC][2 * uC + parC + 1][pjC] = f2bf(gvC ? c[rg] : 0.f);        \
      }                                                                       \
    }                                                                         \
  } while (0)

// ---------------------------------------------------------------------------
// K1-MFMA v14: r7 geometry (6-row strips, 6 waves, split=3, 768 blocks,
// bf16 corr 34 KB, XCD pinning) + 2-deep register pipeline. BARE
// launch_bounds(384): allocator free to take ~130-170 VGPR (spill canary:
// WRITE_SIZE). This is r9's schedule minus the VGPR straitjacket.
// ---------------------------------------------------------------------------
__global__ __launch_bounds__(384) void k_corr_mfma_conv(
    const unsigned short* __restrict__ x0t, const unsigned short* __restrict__ x1t,
    const float* __restrict__ cw, const float* __restrict__ cb,
    float* __restrict__ y0, float* __restrict__ y1, float* __restrict__ y2)
{
    const int L = blockIdx.x;                     // 768 blocks
    const int w = (L & 7) * 96 + (L >> 3);        // bijective XCD swizzle (768=8*96)
    const int b     = w / 96;                     // image b pinned to XCD b
    const int rem   = w % 96;
    const int part  = rem >> 5;                   // 0..2, part-major within image
    const int strip = rem & 31;
    const int i0    = strip * 6;
    const int plo   = (11 * part) / 3;            // 0,3,7
    const int phi   = (11 * (part + 1)) / 3;      // 3,7,11

    const int tid  = threadIdx.x;
    const int wave = tid >> 6, lane = tid & 63;   // wave = ut (u0 fixed)
    const int ln15 = lane & 15, kg = lane >> 4;
    const int u0   = wave * 16;

    __shared__ unsigned short corr[8][194][11];   // bf16; jj=col+1; cols 0,193 zero

    if (tid < 176) {                               // zero pad columns once
        const int ir = tid / 22, rr = tid % 22;
        const int pj = rr % 11, jj = (rr < 11) ? 0 : 193;
        corr[ir][jj][pj] = 0;
    }

    float yacc[3][OC];
#pragma unroll
    for (int k = 0; k < 3; ++k)
#pragma unroll
        for (int o = 0; o < OC; ++o) yacc[k][o] = 0.f;

    const int jt  = tid % 192;                     // conv: column
    const int irb = tid / 192;                     // conv: rows irb, irb+2, irb+4

    const unsigned short* x0b = x0t + (size_t)b * HH * X0ROW;
    const unsigned short* x1b = x1t + (size_t)b * HH * X1ROW;

    for (int pi = plo; pi < phi; ++pi) {
        __syncthreads();                           // conv(pi-1) done with corr

        // ---- MFMA band-GEMM: 16 steps, 2-deep ping-pong pipeline ----
        bf16x8 A0[4], A1[4];
        bf16x8 B0[2][4], B1[2][4];
        LOAD_STEP(A0, B0, pi, 0);
#pragma unroll
        for (int sp = 0; sp < 8; ++sp) {
            LOAD_STEP(A1, B1, pi, 2 * sp + 1);
            COMPUTE_STEP(A0, B0, pi, 2 * sp);
            if (sp < 7) LOAD_STEP(A0, B0, pi, 2 * sp + 2);
            COMPUTE_STEP(A1, B1, pi, 2 * sp + 1);
        }
        __syncthreads();                           // corr slice visible

        // ---- conv(3x3, 121->8), 3 px/thread ----
        for (int ki = 0; ki < 3; ++ki) {
            for (int kj = 0; kj < 3; ++kj) {
                float cv[3][11];
#pragma unroll
                for (int k = 0; k < 3; ++k) {
                    const unsigned short* cp = &corr[irb + 2 * k + ki][jt + kj][0];
#pragma unroll
                    for (int pj = 0; pj < 11; ++pj) cv[k][pj] = bf2f(cp[pj]);
                }
#pragma unroll
                for (int o = 0; o < OC; ++o) {
                    float a0 = yacc[0][o], a1 = yacc[1][o], a2 = yacc[2][o];
#pragma unroll
                    for (int pj = 0; pj < 11; ++pj) {
                        const float wv =               // wave-uniform -> s_load
                            cw[o * 1089 + (pi * 11 + pj) * 9 + ki * 3 + kj];
                        a0 = fmaf(wv, cv[0][pj], a0);
                        a1 = fmaf(wv, cv[1][pj], a1);
                        a2 = fmaf(wv, cv[2][pj], a2);
                    }
                    yacc[0][o] = a0; yacc[1][o] = a1; yacc[2][o] = a2;
                }
            }
        }
    }

    float* yp = (part == 0) ? y0 : ((part == 1) ? y1 : y2);
#pragma unroll
    for (int k = 0; k < 3; ++k) {
        const int irow = i0 + irb + 2 * k;
#pragma unroll
        for (int o = 0; o < OC; ++o) {
            float val = yacc[k][o];
            if (part == 0) val += cb[o];
            yp[((size_t)(b * OC + o) * HH + irow) * WW + jt] = val;
        }
    }
}

// ---------------------------------------------------------------------------
// Fallback K1 (round-1 verified fp32 path) — only if ws too small
// ---------------------------------------------------------------------------
__global__ __launch_bounds__(256) void k_corr_conv(
    const float* __restrict__ x0, const float* __restrict__ x1,
    const float* __restrict__ cw, const float* __restrict__ cb,
    float* __restrict__ y)
{
    const int b  = blockIdx.z;
    const int i0 = blockIdx.y * 14;
    const int j0 = blockIdx.x * 14;
    const int li = threadIdx.x >> 4;
    const int lj = threadIdx.x & 15;
    const int gi = i0 + li - 1;
    const int gj = j0 + lj - 1;
    const bool valid    = (gi >= 0) & (gi < HH) & (gj >= 0) & (gj < WW);
    const bool interior = (li >= 1) & (li <= 14) & (lj >= 1) & (lj <= 14)
                        & (gi < HH) & (gj < WW);

    __shared__ float corr[16][16][13];

    float yacc[OC];
#pragma unroll
    for (int o = 0; o < OC; ++o) yacc[o] = 0.f;

    const size_t bbase = (size_t)b * CC * HW;
    const float* x0p = x0 + bbase + (size_t)gi * WW + gj;

    for (int pi = 0; pi < 11; ++pi) {
        float acc[11];
#pragma unroll
        for (int k = 0; k < 11; ++k) acc[k] = 0.f;

        const int r = gi + 2 * pi - 10;
        if (valid && r >= 0 && r < HH) {
            const float* p0 = x0p;
            if (gj >= 10 && gj <= WW - 11) {
                const float* p1o = x1 + bbase + (size_t)r * WW + (gj - 10);
#pragma unroll 2
                for (int c = 0; c < CC; ++c) {
                    const float a = *p0;
#pragma unroll
                    for (int k = 0; k < 11; ++k)
                        acc[k] = fmaf(a, p1o[2 * k], acc[k]);
                    p0 += HW; p1o += HW;
                }
            } else {
                const float* p1 = x1 + bbase + (size_t)r * WW;
#pragma unroll 2
                for (int c = 0; c < CC; ++c) {
                    const float a = *p0;
#pragma unroll
                    for (int k = 0; k < 11; ++k) {
                        const int col = gj + 2 * k - 10;
                        const float v = (col >= 0 && col < WW) ? p1[col] : 0.f;
                        acc[k] = fmaf(a, v, acc[k]);
                    }
                    p0 += HW; p1 += HW;
                }
            }
        }

        __syncthreads();
#pragma unroll
        for (int k = 0; k < 11; ++k) corr[li][lj][k] = acc[k];
        __syncthreads();

        if (interior) {
#pragma unroll
            for (int ki = 0; ki < 3; ++ki) {
#pragma unroll
                for (int kj = 0; kj < 3; ++kj) {
                    float cv[11];
#pragma unroll
                    for (int k = 0; k < 11; ++k)
                        cv[k] = corr[li + ki - 1][lj + kj - 1][k];
#pragma unroll
                    for (int o = 0; o < OC; ++o) {
#pragma unroll
                        for (int k = 0; k < 11; ++k) {
                            const float wv =
                                cw[(((o * 121) + pi * 11 + k) * 3 + ki) * 3 + kj];
                            yacc[o] = fmaf(wv, cv[k], yacc[o]);
                        }
                    }
                }
            }
        }
    }

    if (interior) {
#pragma unroll
        for (int o = 0; o < OC; ++o)
            y[(size_t)(b * OC + o) * HW + (size_t)gi * WW + gj] = yacc[o] + cb[o];
    }
}

// ---------------------------------------------------------------------------
// BN stats over n partial-y buffers; also materializes the summed y into y0
// (so k_bn_relu reads one buffer). Deterministic two-stage.
// ---------------------------------------------------------------------------
__global__ __launch_bounds__(256) void k_stats_partial(
    float* __restrict__ y0, const float* __restrict__ y1,
    const float* __restrict__ y2, int n, float* __restrict__ st)
{
    const int bid = blockIdx.x;            // b*32 + o*4 + q
    const int b = bid >> 5, rem = bid & 31;
    const int o = rem >> 2, q = rem & 3;
    const size_t off = (size_t)(b * OC + o) * (HW / 4) + q * (HW / 16);
    float4* p0       = (float4*)y0 + off;
    const float4* p1 = (const float4*)y1 + off;
    const float4* p2 = (const float4*)y2 + off;
    float s = 0.f, qq = 0.f;
    for (int t = threadIdx.x; t < HW / 16; t += 256) {
        float4 z = p0[t];
        if (n >= 2) {
            const float4 v = p1[t];
            z.x += v.x; z.y += v.y; z.z += v.z; z.w += v.w;
        }
        if (n >= 3) {
            const float4 v = p2[t];
            z.x += v.x; z.y += v.y; z.z += v.z; z.w += v.w;
        }
        if (n >= 2) p0[t] = z;             // materialize summed y
        s += z.x + z.y + z.z + z.w;
        qq = fmaf(z.x, z.x, qq); qq = fmaf(z.y, z.y, qq);
        qq = fmaf(z.z, z.z, qq); qq = fmaf(z.w, z.w, qq);
    }
#pragma unroll
    for (int off2 = 32; off2 > 0; off2 >>= 1) {
        s  += __shfl_down(s, off2);
        qq += __shfl_down(qq, off2);
    }
    __shared__ float ss[4], sq[4];
    const int lane = threadIdx.x & 63, wv = threadIdx.x >> 6;
    if (lane == 0) { ss[wv] = s; sq[wv] = qq; }
    __syncthreads();
    if (threadIdx.x == 0) {
        st[bid]       = ss[0] + ss[1] + ss[2] + ss[3];
        st[256 + bid] = sq[0] + sq[1] + sq[2] + sq[3];
    }
}

__global__ void k_stats_final(float* __restrict__ st,
                              const float* __restrict__ gamma,
                              const float* __restrict__ beta)
{
    const int o = threadIdx.x;
    if (o < 8) {
        float S = 0.f, Q = 0.f;
#pragma unroll
        for (int b = 0; b < 8; ++b)
#pragma unroll
            for (int q = 0; q < 4; ++q) {
                S += st[b * 32 + o * 4 + q];
                Q += st[256 + b * 32 + o * 4 + q];
            }
        const float invN = 1.f / (float)NPIX;
        const float mean = S * invN;
        const float var  = Q * invN - mean * mean;
        const float sc   = gamma[o] / sqrtf(var + 1e-5f);
        st[512 + o] = sc;
        st[520 + o] = beta[o] - mean * sc;
    }
}

__global__ __launch_bounds__(256) void k_bn_relu(
    float* __restrict__ y, const float* __restrict__ st)
{
    const int i = blockIdx.x * 256 + threadIdx.x;  // float4 idx, exact grid
    const int o = (i / (HW / 4)) & 7;
    const float sc = st[512 + o], sh = st[520 + o];
    float4 v = ((float4*)y)[i];
    v.x = fmaxf(fmaf(v.x, sc, sh), 0.f);
    v.y = fmaxf(fmaf(v.y, sc, sh), 0.f);
    v.z = fmaxf(fmaf(v.z, sc, sh), 0.f);
    v.w = fmaxf(fmaf(v.w, sc, sh), 0.f);
    ((float4*)y)[i] = v;
}

extern "C" void kernel_launch(void* const* d_in, const int* in_sizes, int n_in,
                              void* d_out, int out_size, void* d_ws, size_t ws_size,
                              hipStream_t stream)
{
    const float* x0    = (const float*)d_in[0];
    const float* x1    = (const float*)d_in[1];
    const float* cw    = (const float*)d_in[2];
    const float* cb    = (const float*)d_in[3];
    const float* gamma = (const float*)d_in[4];
    const float* beta  = (const float*)d_in[5];
    float* out = (float*)d_out;
    float* st  = (float*)d_ws;   // stats scratch reuses ws base (x0t dead by then)

    const size_t x0bytes = (size_t)BB * HH * X0ROW * sizeof(unsigned short); // 75.5 MB
    const size_t x1bytes = (size_t)BB * HH * X1ROW * sizeof(unsigned short); // 88.1 MB
    const size_t ybytes  = (size_t)YCHUNK * sizeof(float);                   //  9.4 MB

    if (ws_size >= x0bytes + x1bytes + 2 * ybytes) {
        unsigned short* x0t = (unsigned short*)d_ws;
        unsigned short* x1t = (unsigned short*)((char*)d_ws + x0bytes);
        float* y1 = (float*)((char*)d_ws + x0bytes + x1bytes);
        float* y2 = y1 + YCHUNK;

        k_pack<<<dim3(HH, BB, 2), 256, 0, stream>>>(x0, x1, x0t, x1t);
        k_corr_mfma_conv<<<768, 384, 0, stream>>>(x0t, x1t, cw, cb, out, y1, y2);
        k_stats_partial<<<256, 256, 0, stream>>>(out, y1, y2, 3, st);
        k_stats_final<<<1, 64, 0, stream>>>(st, gamma, beta);
        k_bn_relu<<<(YCHUNK / 4) / 256, 256, 0, stream>>>(out, st);
    } else {
        dim3 g1(14, 14, 8);
        k_corr_conv<<<g1, 256, 0, stream>>>(x0, x1, cw, cb, out);
        k_stats_partial<<<256, 256, 0, stream>>>(out, out, out, 1, st);
        k_stats_final<<<1, 64, 0, stream>>>(st, gamma, beta);
        k_bn_relu<<<(YCHUNK / 4) / 256, 256, 0, stream>>>(out, st);
    }
}

// Round 15
// 522.246 us; speedup vs baseline: 1.1896x; 1.1896x over previous
//
#include <hip/hip_runtime.h>

#define HH 192
#define WW 192
#define CC 128
#define BB 8
#define HW (HH * WW)          // 36864
#define OC 8
#define NPIX (BB * HW)        // 294912 per BN channel
#define YCHUNK (OC * BB * HW) // elements per y buffer
#define X0ROW 24576           // elems per (b,row): 2par*6ut*2048
#define X1ROW 28672           // elems per (b,row): 2par*7vt*2048

typedef __attribute__((ext_vector_type(8))) short bf16x8;
typedef __attribute__((ext_vector_type(4))) float f32x4;

__device__ __forceinline__ unsigned short f2bf(float f) {
    unsigned int u = __float_as_uint(f);
    u += 0x7fffu + ((u >> 16) & 1u);          // RNE
    return (unsigned short)(u >> 16);
}
__device__ __forceinline__ float bf2f(unsigned short u) {
    return __uint_as_float(((unsigned int)u) << 16);
}

// ---------------------------------------------------------------------------
// k_pack: fp32 [b][c][h][w] -> bf16 fragment-ordered tiles (r8/r13-proven
// uint4 version). x0t[b][i]: 12 tiles (par*6+ut) of 2048 elems,
// tile=[q(4)][kg(4)][pxl(16)][e(8)]. x1t[b][r]: 14 tiles (par*7+vt),
// v = 16*vt-8+pxl, zero outside [0,96).
// ---------------------------------------------------------------------------
__global__ __launch_bounds__(256) void k_pack(
    const float* __restrict__ x0, const float* __restrict__ x1,
    unsigned short* __restrict__ x0t, unsigned short* __restrict__ x1t)
{
    const int h = blockIdx.x, b = blockIdx.y, t = blockIdx.z;
    const float* src = t ? x1 : x0;
    __shared__ unsigned short lds[WW * 130];

    for (int idx = threadIdx.x; idx < CC * WW; idx += 256) {
        const int w = idx % WW, c = idx / WW;      // consecutive w per lane
        lds[w * 130 + c] = f2bf(src[((size_t)(b * CC + c) * HH + h) * WW + w]);
    }
    __syncthreads();

    if (t == 0) {
        uint4* dst = (uint4*)(x0t + (size_t)(b * HH + h) * X0ROW);
        for (int f8 = threadIdx.x; f8 < X0ROW / 8; f8 += 256) {
            const int pxl = f8 & 15;
            const int kg  = (f8 >> 4) & 3;
            const int q   = (f8 >> 6) & 3;
            const int pu  = f8 >> 8;               // par*6 + ut
            const int ut  = pu % 6, par = pu / 6;
            const int px  = 2 * (16 * ut + pxl) + par;
            const unsigned short* s0 = &lds[px * 130 + q * 32 + kg * 8];
            uint4 v;
            v.x = s0[0] | ((unsigned int)s0[1] << 16);
            v.y = s0[2] | ((unsigned int)s0[3] << 16);
            v.z = s0[4] | ((unsigned int)s0[5] << 16);
            v.w = s0[6] | ((unsigned int)s0[7] << 16);
            dst[f8] = v;
        }
    } else {
        uint4* dst = (uint4*)(x1t + (size_t)(b * HH + h) * X1ROW);
        for (int f8 = threadIdx.x; f8 < X1ROW / 8; f8 += 256) {
            const int pxl = f8 & 15;
            const int kg  = (f8 >> 4) & 3;
            const int q   = (f8 >> 6) & 3;
            const int pv  = f8 >> 8;               // par*7 + vt
            const int vt  = pv % 7, par = pv / 7;
            const int v   = 16 * vt - 8 + pxl;
            uint4 val = {0u, 0u, 0u, 0u};
            if (v >= 0 && v < 96) {
                const int px = 2 * v + par;
                const unsigned short* s0 = &lds[px * 130 + q * 32 + kg * 8];
                val.x = s0[0] | ((unsigned int)s0[1] << 16);
                val.y = s0[2] | ((unsigned int)s0[3] << 16);
                val.z = s0[4] | ((unsigned int)s0[5] << 16);
                val.w = s0[6] | ((unsigned int)s0[7] << 16);
            }
            dst[f8] = val;
        }
    }
}

// ---------------------------------------------------------------------------
// K1-MFMA (r7 champion, verbatim): 6-row strips, 6 waves, dense fragment
// loads from pre-packed tiles, bf16 corr LDS [8][194][11] (34 KB),
// pi-split=3 (768 blocks = 3/CU), launch_bounds(384,8) -> ~44-48 VGPR,
// bijective XCD swizzle pinning image b to XCD b.
// ---------------------------------------------------------------------------
__global__ __launch_bounds__(384, 8) void k_corr_mfma_conv(
    const unsigned short* __restrict__ x0t, const unsigned short* __restrict__ x1t,
    const float* __restrict__ cw, const float* __restrict__ cb,
    float* __restrict__ y0, float* __restrict__ y1, float* __restrict__ y2)
{
    const int L = blockIdx.x;                     // 768 blocks
    const int w = (L & 7) * 96 + (L >> 3);        // bijective XCD swizzle (768=8*96)
    const int b     = w / 96;                     // image b pinned to XCD b
    const int rem   = w % 96;
    const int part  = rem >> 5;                   // 0..2, part-major within image
    const int strip = rem & 31;
    const int i0    = strip * 6;
    const int plo   = (11 * part) / 3;            // 0,3,7
    const int phi   = (11 * (part + 1)) / 3;      // 3,7,11

    const int tid  = threadIdx.x;
    const int wave = tid >> 6, lane = tid & 63;
    const int ln15 = lane & 15, kg = lane >> 4;

    __shared__ unsigned short corr[8][194][11];   // bf16; jj=col+1; cols 0,193 zero

    if (tid < 176) {                               // zero pad columns once
        const int ir = tid / 22, rr = tid % 22;
        const int pj = rr % 11, jj = (rr < 11) ? 0 : 193;
        corr[ir][jj][pj] = 0;
    }

    float yacc[3][OC];
#pragma unroll
    for (int k = 0; k < 3; ++k)
#pragma unroll
        for (int o = 0; o < OC; ++o) yacc[k][o] = 0.f;

    const int jt  = tid % 192;                     // conv: column
    const int irb = tid / 192;                     // conv: rows irb, irb+2, irb+4

    const unsigned short* x0b = x0t + (size_t)b * HH * X0ROW;
    const unsigned short* x1b = x1t + (size_t)b * HH * X1ROW;

    for (int pi = plo; pi < phi; ++pi) {
        __syncthreads();                           // conv(pi-1) done with corr

        // ---------------- MFMA band-GEMM phase: 96 groups ----------------
        for (int g = wave; g < 96; g += 6) {
            const int ir  = g / 12, rr = g % 12;
            const int par = rr / 6, ut = rr % 6;
            const int u0  = ut * 16;
            const int i   = i0 - 1 + ir;
            const int r   = i + 2 * pi - 10;
            const bool gv = (i >= 0) && (i < HH) && (r >= 0) && (r < HH);
            const int icl = min(max(i, 0), HH - 1);
            const int rcl = min(max(r, 0), HH - 1);

            const unsigned short* pa =
                x0b + (size_t)icl * X0ROW + (par * 6 + ut) * 2048 + lane * 8;
            const bf16x8 a0 = *(const bf16x8*)(pa);
            const bf16x8 a1 = *(const bf16x8*)(pa + 512);
            const bf16x8 a2 = *(const bf16x8*)(pa + 1024);
            const bf16x8 a3 = *(const bf16x8*)(pa + 1536);

#pragma unroll
            for (int vtl = 0; vtl < 2; ++vtl) {
                const unsigned short* pb =
                    x1b + (size_t)rcl * X1ROW + (par * 7 + ut + vtl) * 2048 + lane * 8;
                const bf16x8 b0 = *(const bf16x8*)(pb);
                const bf16x8 b1 = *(const bf16x8*)(pb + 512);
                const bf16x8 b2 = *(const bf16x8*)(pb + 1024);
                const bf16x8 b3 = *(const bf16x8*)(pb + 1536);

                f32x4 c = {0.f, 0.f, 0.f, 0.f};
                c = __builtin_amdgcn_mfma_f32_16x16x32_bf16(a0, b0, c, 0, 0, 0);
                c = __builtin_amdgcn_mfma_f32_16x16x32_bf16(a1, b1, c, 0, 0, 0);
                c = __builtin_amdgcn_mfma_f32_16x16x32_bf16(a2, b2, c, 0, 0, 0);
                c = __builtin_amdgcn_mfma_f32_16x16x32_bf16(a3, b3, c, 0, 0, 0);

                const int v = u0 - 8 + 16 * vtl + ln15;    // x1 zeros cover OOB v
#pragma unroll
                for (int rg = 0; rg < 4; ++rg) {
                    const int u  = u0 + kg * 4 + rg;
                    const int pj = v - u + 5;
                    if (pj >= 0 && pj < 11)
                        corr[ir][2 * u + par + 1][pj] = f2bf(gv ? c[rg] : 0.f);
                }
            }
        }
        __syncthreads();                           // corr slice visible

        // ---------------- conv(3x3, 121->8), 3 px/thread -----------------
        for (int ki = 0; ki < 3; ++ki) {
            for (int kj = 0; kj < 3; ++kj) {
                float cv[3][11];
#pragma unroll
                for (int k = 0; k < 3; ++k) {
                    const unsigned short* cp = &corr[irb + 2 * k + ki][jt + kj][0];
#pragma unroll
                    for (int pj = 0; pj < 11; ++pj) cv[k][pj] = bf2f(cp[pj]);
                }
#pragma unroll
                for (int o = 0; o < OC; ++o) {
                    float a0 = yacc[0][o], a1 = yacc[1][o], a2 = yacc[2][o];
#pragma unroll
                    for (int pj = 0; pj < 11; ++pj) {
                        const float wv =               // wave-uniform -> s_load
                            cw[o * 1089 + (pi * 11 + pj) * 9 + ki * 3 + kj];
                        a0 = fmaf(wv, cv[0][pj], a0);
                        a1 = fmaf(wv, cv[1][pj], a1);
                        a2 = fmaf(wv, cv[2][pj], a2);
                    }
                    yacc[0][o] = a0; yacc[1][o] = a1; yacc[2][o] = a2;
                }
            }
        }
    }

    float* yp = (part == 0) ? y0 : ((part == 1) ? y1 : y2);
#pragma unroll
    for (int k = 0; k < 3; ++k) {
        const int irow = i0 + irb + 2 * k;
#pragma unroll
        for (int o = 0; o < OC; ++o) {
            float val = yacc[k][o];
            if (part == 0) val += cb[o];
            yp[((size_t)(b * OC + o) * HH + irow) * WW + jt] = val;
        }
    }
}

// ---------------------------------------------------------------------------
// Fallback K1 (round-1 verified fp32 path) — only if ws too small
// ---------------------------------------------------------------------------
__global__ __launch_bounds__(256) void k_corr_conv(
    const float* __restrict__ x0, const float* __restrict__ x1,
    const float* __restrict__ cw, const float* __restrict__ cb,
    float* __restrict__ y)
{
    const int b  = blockIdx.z;
    const int i0 = blockIdx.y * 14;
    const int j0 = blockIdx.x * 14;
    const int li = threadIdx.x >> 4;
    const int lj = threadIdx.x & 15;
    const int gi = i0 + li - 1;
    const int gj = j0 + lj - 1;
    const bool valid    = (gi >= 0) & (gi < HH) & (gj >= 0) & (gj < WW);
    const bool interior = (li >= 1) & (li <= 14) & (lj >= 1) & (lj <= 14)
                        & (gi < HH) & (gj < WW);

    __shared__ float corr[16][16][13];

    float yacc[OC];
#pragma unroll
    for (int o = 0; o < OC; ++o) yacc[o] = 0.f;

    const size_t bbase = (size_t)b * CC * HW;
    const float* x0p = x0 + bbase + (size_t)gi * WW + gj;

    for (int pi = 0; pi < 11; ++pi) {
        float acc[11];
#pragma unroll
        for (int k = 0; k < 11; ++k) acc[k] = 0.f;

        const int r = gi + 2 * pi - 10;
        if (valid && r >= 0 && r < HH) {
            const float* p0 = x0p;
            if (gj >= 10 && gj <= WW - 11) {
                const float* p1o = x1 + bbase + (size_t)r * WW + (gj - 10);
#pragma unroll 2
                for (int c = 0; c < CC; ++c) {
                    const float a = *p0;
#pragma unroll
                    for (int k = 0; k < 11; ++k)
                        acc[k] = fmaf(a, p1o[2 * k], acc[k]);
                    p0 += HW; p1o += HW;
                }
            } else {
                const float* p1 = x1 + bbase + (size_t)r * WW;
#pragma unroll 2
                for (int c = 0; c < CC; ++c) {
                    const float a = *p0;
#pragma unroll
                    for (int k = 0; k < 11; ++k) {
                        const int col = gj + 2 * k - 10;
                        const float v = (col >= 0 && col < WW) ? p1[col] : 0.f;
                        acc[k] = fmaf(a, v, acc[k]);
                    }
                    p0 += HW; p1 += HW;
                }
            }
        }

        __syncthreads();
#pragma unroll
        for (int k = 0; k < 11; ++k) corr[li][lj][k] = acc[k];
        __syncthreads();

        if (interior) {
#pragma unroll
            for (int ki = 0; ki < 3; ++ki) {
#pragma unroll
                for (int kj = 0; kj < 3; ++kj) {
                    float cv[11];
#pragma unroll
                    for (int k = 0; k < 11; ++k)
                        cv[k] = corr[li + ki - 1][lj + kj - 1][k];
#pragma unroll
                    for (int o = 0; o < OC; ++o) {
#pragma unroll
                        for (int k = 0; k < 11; ++k) {
                            const float wv =
                                cw[(((o * 121) + pi * 11 + k) * 3 + ki) * 3 + kj];
                            yacc[o] = fmaf(wv, cv[k], yacc[o]);
                        }
                    }
                }
            }
        }
    }

    if (interior) {
#pragma unroll
        for (int o = 0; o < OC; ++o)
            y[(size_t)(b * OC + o) * HW + (size_t)gi * WW + gj] = yacc[o] + cb[o];
    }
}

// ---------------------------------------------------------------------------
// BN stats over n partial-y buffers; materializes summed y into y0 so the
// apply pass reads one buffer (r14-verified). Deterministic two-stage.
// ---------------------------------------------------------------------------
__global__ __launch_bounds__(256) void k_stats_partial(
    float* __restrict__ y0, const float* __restrict__ y1,
    const float* __restrict__ y2, int n, float* __restrict__ st)
{
    const int bid = blockIdx.x;            // b*32 + o*4 + q
    const int b = bid >> 5, rem = bid & 31;
    const int o = rem >> 2, q = rem & 3;
    const size_t off = (size_t)(b * OC + o) * (HW / 4) + q * (HW / 16);
    float4* p0       = (float4*)y0 + off;
    const float4* p1 = (const float4*)y1 + off;
    const float4* p2 = (const float4*)y2 + off;
    float s = 0.f, qq = 0.f;
    for (int t = threadIdx.x; t < HW / 16; t += 256) {
        float4 z = p0[t];
        if (n >= 2) {
            const float4 v = p1[t];
            z.x += v.x; z.y += v.y; z.z += v.z; z.w += v.w;
        }
        if (n >= 3) {
            const float4 v = p2[t];
            z.x += v.x; z.y += v.y; z.z += v.z; z.w += v.w;
        }
        if (n >= 2) p0[t] = z;             // materialize summed y
        s += z.x + z.y + z.z + z.w;
        qq = fmaf(z.x, z.x, qq); qq = fmaf(z.y, z.y, qq);
        qq = fmaf(z.z, z.z, qq); qq = fmaf(z.w, z.w, qq);
    }
#pragma unroll
    for (int off2 = 32; off2 > 0; off2 >>= 1) {
        s  += __shfl_down(s, off2);
        qq += __shfl_down(qq, off2);
    }
    __shared__ float ss[4], sq[4];
    const int lane = threadIdx.x & 63, wv = threadIdx.x >> 6;
    if (lane == 0) { ss[wv] = s; sq[wv] = qq; }
    __syncthreads();
    if (threadIdx.x == 0) {
        st[bid]       = ss[0] + ss[1] + ss[2] + ss[3];
        st[256 + bid] = sq[0] + sq[1] + sq[2] + sq[3];
    }
}

__global__ void k_stats_final(float* __restrict__ st,
                              const float* __restrict__ gamma,
                              const float* __restrict__ beta)
{
    const int o = threadIdx.x;
    if (o < 8) {
        float S = 0.f, Q = 0.f;
#pragma unroll
        for (int b = 0; b < 8; ++b)
#pragma unroll
            for (int q = 0; q < 4; ++q) {
                S += st[b * 32 + o * 4 + q];
                Q += st[256 + b * 32 + o * 4 + q];
            }
        const float invN = 1.f / (float)NPIX;
        const float mean = S * invN;
        const float var  = Q * invN - mean * mean;
        const float sc   = gamma[o] / sqrtf(var + 1e-5f);
        st[512 + o] = sc;
        st[520 + o] = beta[o] - mean * sc;
    }
}

__global__ __launch_bounds__(256) void k_bn_relu(
    float* __restrict__ y, const float* __restrict__ st)
{
    const int i = blockIdx.x * 256 + threadIdx.x;  // float4 idx, exact grid
    const int o = (i / (HW / 4)) & 7;
    const float sc = st[512 + o], sh = st[520 + o];
    float4 v = ((float4*)y)[i];
    v.x = fmaxf(fmaf(v.x, sc, sh), 0.f);
    v.y = fmaxf(fmaf(v.y, sc, sh), 0.f);
    v.z = fmaxf(fmaf(v.z, sc, sh), 0.f);
    v.w = fmaxf(fmaf(v.w, sc, sh), 0.f);
    ((float4*)y)[i] = v;
}

extern "C" void kernel_launch(void* const* d_in, const int* in_sizes, int n_in,
                              void* d_out, int out_size, void* d_ws, size_t ws_size,
                              hipStream_t stream)
{
    const float* x0    = (const float*)d_in[0];
    const float* x1    = (const float*)d_in[1];
    const float* cw    = (const float*)d_in[2];
    const float* cb    = (const float*)d_in[3];
    const float* gamma = (const float*)d_in[4];
    const float* beta  = (const float*)d_in[5];
    float* out = (float*)d_out;
    float* st  = (float*)d_ws;   // stats scratch reuses ws base (x0t dead by then)

    const size_t x0bytes = (size_t)BB * HH * X0ROW * sizeof(unsigned short); // 75.5 MB
    const size_t x1bytes = (size_t)BB * HH * X1ROW * sizeof(unsigned short); // 88.1 MB
    const size_t ybytes  = (size_t)YCHUNK * sizeof(float);                   //  9.4 MB

    if (ws_size >= x0bytes + x1bytes + 2 * ybytes) {
        unsigned short* x0t = (unsigned short*)d_ws;
        unsigned short* x1t = (unsigned short*)((char*)d_ws + x0bytes);
        float* y1 = (float*)((char*)d_ws + x0bytes + x1bytes);
        float* y2 = y1 + YCHUNK;

        k_pack<<<dim3(HH, BB, 2), 256, 0, stream>>>(x0, x1, x0t, x1t);
        k_corr_mfma_conv<<<768, 384, 0, stream>>>(x0t, x1t, cw, cb, out, y1, y2);
        k_stats_partial<<<256, 256, 0, stream>>>(out, y1, y2, 3, st);
        k_stats_final<<<1, 64, 0, stream>>>(st, gamma, beta);
        k_bn_relu<<<(YCHUNK / 4) / 256, 256, 0, stream>>>(out, st);
    } else {
        dim3 g1(14, 14, 8);
        k_corr_conv<<<g1, 256, 0, stream>>>(x0, x1, cw, cb, out);
        k_stats_partial<<<256, 256, 0, stream>>>(out, out, out, 1, st);
        k_stats_final<<<1, 64, 0, stream>>>(st, gamma, beta);
        k_bn_relu<<<(YCHUNK / 4) / 256, 256, 0, stream>>>(out, st);
    }
}